// Round 8
// baseline (164.137 us; speedup 1.0000x reference)
//
#include <hip/hip_runtime.h>

#define N_TOKENS 32768
#define K_CODES  1024
#define DIM      256
#define BETA     0.25f

typedef unsigned long long u64;
typedef _Float16 half8 __attribute__((ext_vector_type(8)));
typedef float floatx4 __attribute__((ext_vector_type(4)));

// XOR swizzle: 16-B granule g of row r stored at granule g ^ ((r ^ r>>2) & 3).
// Enumerated bank pattern for both frag reads (lanes = 16 rows x 4 k-groups)
// and staging stores (16 rows x 4 granules): every 4-bank group hit by exactly
// 2 lanes -> 2-way aliasing = free (m136). Keeps 16-B alignment (unlike
// odd-stride padding, which breaks ds_read_b128).
__device__ __forceinline__ int gsw(int row, int g) {
    return g ^ ((row ^ (row >> 2)) & 3);
}

// ---- init: wn[k]=||w_k||^2 (fp32 exact), counts=0, keys=+inf, w->hi/lo fp16 --
__global__ void init_kernel(const float* __restrict__ w, float* __restrict__ wn,
                            int* __restrict__ counts, u64* __restrict__ keys,
                            _Float16* __restrict__ whiG, _Float16* __restrict__ wloG) {
    int k = blockIdx.x;
    int lane = threadIdx.x;  // 64
    float4 v = *(const float4*)(w + (size_t)k * DIM + lane * 4);
    float vals[4] = {v.x, v.y, v.z, v.w};
    float s = 0.f;
    #pragma unroll
    for (int e = 0; e < 4; e++) {
        s += vals[e] * vals[e];
        _Float16 h = (_Float16)vals[e];
        whiG[k * DIM + lane * 4 + e] = h;
        wloG[k * DIM + lane * 4 + e] = (_Float16)(vals[e] - (float)h);
    }
    #pragma unroll
    for (int off = 32; off; off >>= 1) s += __shfl_down(s, off);
    if (lane == 0) { wn[k] = s; counts[k] = 0; }
    if (lane < 32) keys[k * 32 + lane] = ~0ull;   // 1024*32 = 32768 keys
}

// ---------------- argmin: fp16-split MFMA distance GEMM + atomicMin merge ----
// dot(z,w) = hi_z*hi_w + hi_z*lo_w + lo_z*hi_w  (lo*lo dropped, err ~1e-5).
// grid = 8 code-eighths x 256 token-tiles. Block: 128 tok x 128 codes, 4 waves,
// wave tile 64x64 (16 MFMA tiles x 3 products per K32 chunk).
// Occupancy is the design driver (r7 lesson: VGPR_Count omits the 128 AGPRs;
// 64x128 tile = 252 total regs = 2 waves/SIMD cap). Here: acc 64 AGPR +
// ~90 VGPR < 170 -> 3 waves/SIMD; LDS 32,768 B packed (XOR swizzle, no pad)
// -> 3 blocks/CU -> 12 waves/CU (vs 8 in r7).
__global__ __launch_bounds__(256, 3) void argmin_kernel(
    const float* __restrict__ z, const _Float16* __restrict__ whiG,
    const _Float16* __restrict__ wloG, const float* __restrict__ wn,
    u64* __restrict__ keys)
{
    __shared__ _Float16 zhi[128 * 32], zlo[128 * 32];   // 8 KB each
    __shared__ _Float16 whi[128 * 32], wlo[128 * 32];   // 8 KB each

    const int tid  = threadIdx.x;
    const int lane = tid & 63;
    const int wid  = tid >> 6;          // 0..3
    const int wm   = wid >> 1;          // token half (64)
    const int wq   = wid & 1;           // code half (64)
    const int t_   = blockIdx.x & 255;  // token tile
    const int q    = blockIdx.x >> 8;   // code eighth 0..7
    const int tok0  = t_ * 128;
    const int kbase = q * 128;

    const int n  = lane & 15;           // code/frag column
    const int kg = lane >> 4;           // k-group 0..3
    const int ga = kg ^ ((n ^ (n >> 2)) & 3);   // frag granule (row-bits of n only)

    // wn for this thread's 4 code columns (L2-warm from init)
    float wnv[4];
    #pragma unroll
    for (int j = 0; j < 4; j++)
        wnv[j] = wn[kbase + wq * 64 + j * 16 + n];

    floatx4 acc[4][4];
    #pragma unroll
    for (int i = 0; i < 4; i++)
        #pragma unroll
        for (int j = 0; j < 4; j++)
            acc[i][j] = (floatx4){0.f, 0.f, 0.f, 0.f};

    const int r0 = tid >> 2;   // staging row (0..63), +64 for s=1
    const int g0 = tid & 3;    // granule within 32-half chunk row

    for (int dt = 0; dt < 8; ++dt) {
        const int d0 = dt * 32;
        __syncthreads();   // previous chunk's fragment reads done

        // stage z chunk (128 tok x 32 d): fp32 -> (hi,lo) fp16, swizzled store
        #pragma unroll
        for (int s = 0; s < 2; s++) {
            int t = r0 + s * 64;
            const float* p = z + (size_t)(tok0 + t) * DIM + d0 + g0 * 8;
            float4 a = *(const float4*)p;
            float4 b = *(const float4*)(p + 4);
            float vals[8] = {a.x, a.y, a.z, a.w, b.x, b.y, b.z, b.w};
            half8 hv, lv;
            #pragma unroll
            for (int e = 0; e < 8; e++) {
                _Float16 h = (_Float16)vals[e];
                hv[e] = h;
                lv[e] = (_Float16)(vals[e] - (float)h);
            }
            int off = t * 32 + gsw(t, g0) * 8;
            *(half8*)&zhi[off] = hv;
            *(half8*)&zlo[off] = lv;
        }
        // stage w chunk (128 codes x 32 d): pre-split fp16, pure swizzled copy
        #pragma unroll
        for (int s = 0; s < 2; s++) {
            int t = r0 + s * 64;
            size_t goff = (size_t)(kbase + t) * DIM + d0 + g0 * 8;
            int off = t * 32 + gsw(t, g0) * 8;
            *(half8*)&whi[off] = *(const half8*)&whiG[goff];
            *(half8*)&wlo[off] = *(const half8*)&wloG[goff];
        }
        __syncthreads();

        // fragments: A[m=n][k=kg*8+e], B[k][n]
        half8 ah[4], al[4];
        #pragma unroll
        for (int i = 0; i < 4; i++) {
            int off = (wm * 64 + i * 16 + n) * 32 + ga * 8;
            ah[i] = *(const half8*)&zhi[off];
            al[i] = *(const half8*)&zlo[off];
        }
        #pragma unroll
        for (int j = 0; j < 4; j++) {
            int off = (wq * 64 + j * 16 + n) * 32 + ga * 8;
            half8 bh = *(const half8*)&whi[off];
            half8 bl = *(const half8*)&wlo[off];
            #pragma unroll
            for (int i = 0; i < 4; i++) {
                acc[i][j] = __builtin_amdgcn_mfma_f32_16x16x32_f16(ah[i], bh, acc[i][j], 0, 0, 0);
                acc[i][j] = __builtin_amdgcn_mfma_f32_16x16x32_f16(ah[i], bl, acc[i][j], 0, 0, 0);
                acc[i][j] = __builtin_amdgcn_mfma_f32_16x16x32_f16(al[i], bh, acc[i][j], 0, 0, 0);
            }
        }
    }

    // epilogue: dist = wn[code] - 2*dot (||z||^2 constant per row).
    // C layout: col(code) = n, row(token) = kg*4 + reg.
    #pragma unroll
    for (int i = 0; i < 4; i++) {
        #pragma unroll
        for (int r = 0; r < 4; r++) {
            float bv = 3.4e38f; int bi = 0;
            #pragma unroll
            for (int j = 0; j < 4; j++) {
                float dist = wnv[j] - 2.0f * acc[i][j][r];
                if (dist < bv) { bv = dist; bi = kbase + wq * 64 + j * 16 + n; }
            }
            unsigned uu = __float_as_uint(bv);
            unsigned ss = (uu & 0x80000000u) ? ~uu : (uu | 0x80000000u);
            u64 key = ((u64)ss << 32) | (unsigned)bi;
            #pragma unroll
            for (int m = 1; m < 16; m <<= 1) {
                u64 o = __shfl_xor(key, m);
                if (o < key) key = o;
            }
            if (n == 0) {
                int token = tok0 + wm * 64 + i * 16 + kg * 4 + r;
                atomicMin(&keys[token], key);
            }
        }
    }
}

// ---------------- gather + commitment loss + idx/counts ----------------
// wave (64 lanes) = one token (64 float4). 8192 waves x 4 iters.
// Keys loaded by all lanes (same-address broadcast) and hoisted upfront for MLP.
__global__ void gather_loss_kernel(const float* __restrict__ z,
                                   const float* __restrict__ w,
                                   const u64* __restrict__ keys,
                                   float* __restrict__ zq_out,
                                   float* __restrict__ idxf,
                                   int* __restrict__ counts,
                                   float* __restrict__ partials)
{
    __shared__ float red[4];
    int tid = threadIdx.x;
    int lane = tid & 63;
    int wid = blockIdx.x * 4 + (tid >> 6);   // 0..8191
    u64 k4[4];
    #pragma unroll
    for (int it = 0; it < 4; it++)
        k4[it] = keys[wid + it * 8192];
    float s = 0.0f;
    #pragma unroll
    for (int it = 0; it < 4; it++) {
        int tok = wid + it * 8192;
        int k = (int)(unsigned)(k4[it] & 0xFFFFFFFFull);
        float4 wv = *(const float4*)(w + (size_t)k * DIM + lane * 4);
        float4 zv = *(const float4*)(z + (size_t)tok * DIM + lane * 4);
        *(float4*)(zq_out + (size_t)tok * DIM + lane * 4) = wv;
        float dx = wv.x - zv.x, dy = wv.y - zv.y, dz = wv.z - zv.z, dw = wv.w - zv.w;
        s += dx * dx + dy * dy + dz * dz + dw * dw;
        if (lane == 0) {
            idxf[tok] = (float)k;
            atomicAdd(&counts[k], 1);
        }
    }
    #pragma unroll
    for (int off = 32; off; off >>= 1) s += __shfl_down(s, off);
    if (lane == 0) red[tid >> 6] = s;
    __syncthreads();
    if (tid == 0)
        partials[blockIdx.x] = red[0] + red[1] + red[2] + red[3];
}

// ---------------- perplexity + loss finalize ----------------
__global__ void finalize_kernel(const int* __restrict__ counts,
                                const float* __restrict__ partials,
                                float* __restrict__ loss_out,
                                float* __restrict__ ppl_out)
{
    __shared__ float redE[16], redL[16];
    int tid = threadIdx.x;  // 1024
    float e = (float)counts[tid] * (1.0f / (float)N_TOKENS);
    float t = -e * logf(e + 1e-10f);
    float p = partials[tid] + partials[tid + 1024];
    #pragma unroll
    for (int off = 32; off; off >>= 1) {
        t += __shfl_down(t, off);
        p += __shfl_down(p, off);
    }
    if ((tid & 63) == 0) { redE[tid >> 6] = t; redL[tid >> 6] = p; }
    __syncthreads();
    if (tid == 0) {
        float se = 0.0f, sl = 0.0f;
        #pragma unroll
        for (int i = 0; i < 16; i++) { se += redE[i]; sl += redL[i]; }
        *ppl_out = expf(se);
        *loss_out = BETA * sl / (float)((size_t)N_TOKENS * DIM);
    }
}

extern "C" void kernel_launch(void* const* d_in, const int* in_sizes, int n_in,
                              void* d_out, int out_size, void* d_ws, size_t ws_size,
                              hipStream_t stream) {
    const float* z = (const float*)d_in[0];
    const float* w = (const float*)d_in[1];
    float* out = (float*)d_out;

    // d_out layout (float): [0]=loss, [1..NT*D]=z_q_st, [..]=indices(float), [last]=perplexity
    float* loss_out = out;
    float* zq_out   = out + 1;
    float* idxf     = out + 1 + (size_t)N_TOKENS * DIM;
    float* ppl_out  = out + (out_size - 1);

    // ws layout: wn f32[1024] | counts i32[1024] | partials f32[2048]
    //            | keys u64[32768] @ byte 16384 | whiG/wloG fp16[1024*256] after
    float* wn       = (float*)d_ws;
    int*   counts   = (int*)d_ws + 1024;
    float* partials = (float*)d_ws + 2048;
    u64*   keys     = (u64*)((char*)d_ws + 16384);
    _Float16* whiG  = (_Float16*)((char*)d_ws + 16384 + (size_t)N_TOKENS * 8);
    _Float16* wloG  = whiG + (size_t)K_CODES * DIM;

    init_kernel<<<K_CODES, 64, 0, stream>>>(w, wn, counts, keys, whiG, wloG);
    argmin_kernel<<<8 * 256, 256, 0, stream>>>(z, whiG, wloG, wn, keys);
    gather_loss_kernel<<<2048, 256, 0, stream>>>(z, w, keys, zq_out, idxf, counts, partials);
    finalize_kernel<<<1, 1024, 0, stream>>>(counts, partials, loss_out, ppl_out);
}